// Round 1
// baseline (302.216 us; speedup 1.0000x reference)
//
#include <hip/hip_runtime.h>

#define TPB 256
#define PPT 4

namespace {
constexpr int B = 8, F = 6, NB = 5, NS = 7, H = 192, W = 192, C = 3;
constexpr int FM1 = F - 1;                         // 5 frames used (skip f=0)
constexpr int HW = H * W;                          // 36864
constexpr int PAIRS = B * FM1;                     // 40 (b,f) pairs
constexpr int BLOCKS_PER_PAIR = HW / (TPB * PPT);  // 36
constexpr float EPS = 1e-7f;
}

__global__ __launch_bounds__(TPB) void em_rec_loss_kernel(
    const float* __restrict__ seg,    // [B,F,NB,H,W]
    const float* __restrict__ masks,  // [B,F,NS,H,W]
    const float* __restrict__ recon,  // [B,F,NB,C,H,W]
    const float* __restrict__ rtgt,   // [B,F,C,H,W]
    const float* __restrict__ vis,    // [B,F,NS,H,W]
    const float* __restrict__ attn,   // [B,F,NS,NB]
    float* __restrict__ out)          // scalar
{
  const int blk = blockIdx.x;
  const int pair = blk / BLOCKS_PER_PAIR;
  const int chunk = blk - pair * BLOCKS_PER_PAIR;
  const int b = pair / FM1;
  const int f = pair - b * FM1 + 1;   // frames 1..F-1
  const int bf = b * F + f;

  // attn[b,f,s,n] is block-uniform: keep in registers (scalarizes to s_load)
  float a[NS][NB];
  const float* at = attn + (size_t)bf * NS * NB;
  #pragma unroll
  for (int s = 0; s < NS; ++s)
    #pragma unroll
    for (int n = 0; n < NB; ++n)
      a[s][n] = at[s * NB + n];

  float A[NB];  // A[n] = sum_s attn[s][n]  (weights the ce_base term)
  #pragma unroll
  for (int n = 0; n < NB; ++n) {
    float t = 0.f;
    #pragma unroll
    for (int s = 0; s < NS; ++s) t += a[s][n];
    A[n] = t;
  }

  const float* segp = seg   + (size_t)bf * NB * HW;
  const float* mp   = masks + (size_t)bf * NS * HW;
  const float* vp   = vis   + (size_t)bf * NS * HW;
  const float* rp   = recon + (size_t)bf * NB * C * HW;
  const float* tp   = rtgt  + (size_t)bf * C * HW;

  constexpr float INV_HW = 1.0f / (float)HW;
  constexpr float COEF = 0.1f / (float)C;

  float acc = 0.f;
  const int pix0 = chunk * (TPB * PPT) + threadIdx.x;

  #pragma unroll
  for (int j = 0; j < PPT; ++j) {
    const int pix = pix0 + j * TPB;  // stride-1 across lanes -> coalesced

    // wt[n] = sum_s attn[s][n]*t_s ; wv[n] = sum_s attn[s][n]*vis_s
    float wt[NB], wv[NB];
    #pragma unroll
    for (int n = 0; n < NB; ++n) { wt[n] = 0.f; wv[n] = 0.f; }
    #pragma unroll
    for (int s = 0; s < NS; ++s) {
      const float ts = (mp[s * HW + pix] > 0.5f) ? 1.f : 0.f;
      const float vs = (vp[s * HW + pix] > 0.5f) ? 1.f : 0.f;
      #pragma unroll
      for (int n = 0; n < NB; ++n) {
        wt[n] = fmaf(a[s][n], ts, wt[n]);
        wv[n] = fmaf(a[s][n], vs, wv[n]);
      }
    }

    float tg[C];
    #pragma unroll
    for (int c = 0; c < C; ++c) tg[c] = tp[c * HW + pix];

    #pragma unroll
    for (int n = 0; n < NB; ++n) {
      float p = segp[n * HW + pix];
      p = fminf(fmaxf(p, EPS), 1.0f - EPS);
      const float l1 = log1pf(-p);       // log(1-p)
      const float lp = logf(p);          // log(p)
      float d2 = 0.f;
      #pragma unroll
      for (int c = 0; c < C; ++c) {
        const float d = rp[(n * C + c) * HW + pix] - tg[c];
        d2 = fmaf(d, d, d2);
      }
      // bce part: -((lp-l1)*wt + l1*A)/HW ; mse part: (0.1/C)*d2*wv
      acc += -((lp - l1) * wt[n] + l1 * A[n]) * INV_HW + COEF * d2 * wv[n];
    }
  }

  // wave(64) shuffle reduce -> LDS across 4 waves -> one atomic per block
  #pragma unroll
  for (int off = 32; off > 0; off >>= 1)
    acc += __shfl_down(acc, off, 64);

  __shared__ float wsum[TPB / 64];
  const int lane = threadIdx.x & 63;
  const int wid = threadIdx.x >> 6;
  if (lane == 0) wsum[wid] = acc;
  __syncthreads();
  if (threadIdx.x == 0) {
    float s = 0.f;
    #pragma unroll
    for (int i = 0; i < TPB / 64; ++i) s += wsum[i];
    constexpr float SCALE = 20.0f / (float)(B * FM1 * NB * NS);  // 20/1400
    atomicAdd(out, s * SCALE);
  }
}

extern "C" void kernel_launch(void* const* d_in, const int* in_sizes, int n_in,
                              void* d_out, int out_size, void* d_ws, size_t ws_size,
                              hipStream_t stream) {
  const float* seg   = (const float*)d_in[0];  // segmentations
  const float* masks = (const float*)d_in[1];  // masks
  const float* recon = (const float*)d_in[2];  // reconstructions
  const float* rtgt  = (const float*)d_in[3];  // rec_tgt
  const float* vis   = (const float*)d_in[4];  // masks_vis
  const float* attn  = (const float*)d_in[5];  // attn_index
  // d_in[6] slots, d_in[7] pred_slots: unused by the reference

  float* out = (float*)d_out;
  hipMemsetAsync(out, 0, sizeof(float), stream);  // d_out is poisoned 0xAA

  const int grid = PAIRS * BLOCKS_PER_PAIR;  // 1440 blocks
  em_rec_loss_kernel<<<grid, TPB, 0, stream>>>(seg, masks, recon, rtgt, vis, attn, out);
}

// Round 2
// 263.782 us; speedup vs baseline: 1.1457x; 1.1457x over previous
//
#include <hip/hip_runtime.h>

#define TPB 256

namespace {
constexpr int B = 8, F = 6, NB = 5, NS = 7, H = 192, W = 192, C = 3;
constexpr int FM1 = F - 1;                 // frames 1..5
constexpr int HW = H * W;                  // 36864
constexpr int HW4 = HW / 4;                // 9216 float4 per plane
constexpr int PAIRS = B * FM1;             // 40
constexpr int BLOCKS_PER_PAIR = HW4 / TPB; // 36
constexpr float EPS = 1e-7f;
}

__device__ __forceinline__ float4 step05(float4 v) {
  return make_float4(v.x > 0.5f ? 1.f : 0.f, v.y > 0.5f ? 1.f : 0.f,
                     v.z > 0.5f ? 1.f : 0.f, v.w > 0.5f ? 1.f : 0.f);
}
__device__ __forceinline__ void fma4(float4& acc, float s, const float4& v) {
  acc.x = fmaf(s, v.x, acc.x); acc.y = fmaf(s, v.y, acc.y);
  acc.z = fmaf(s, v.z, acc.z); acc.w = fmaf(s, v.w, acc.w);
}

__global__ __launch_bounds__(TPB) void em_rec_loss_kernel(
    const float* __restrict__ seg,    // [B,F,NB,H,W]
    const float* __restrict__ masks,  // [B,F,NS,H,W]
    const float* __restrict__ recon,  // [B,F,NB,C,H,W]
    const float* __restrict__ rtgt,   // [B,F,C,H,W]
    const float* __restrict__ vis,    // [B,F,NS,H,W]
    const float* __restrict__ attn,   // [B,F,NS,NB]
    float* __restrict__ out)
{
  const int blk = blockIdx.x;
  const int pair = blk / BLOCKS_PER_PAIR;
  const int chunk = blk - pair * BLOCKS_PER_PAIR;
  const int b = pair / FM1;
  const int f = pair - b * FM1 + 1;
  const int bf = b * F + f;

  // block-uniform attn weights -> SGPRs (compiler scalarizes uniform loads)
  float a[NS][NB];
  const float* at = attn + (size_t)bf * NS * NB;
  #pragma unroll
  for (int s = 0; s < NS; ++s)
    #pragma unroll
    for (int n = 0; n < NB; ++n)
      a[s][n] = at[s * NB + n];

  float A[NB];
  #pragma unroll
  for (int n = 0; n < NB; ++n) {
    float t = 0.f;
    #pragma unroll
    for (int s = 0; s < NS; ++s) t += a[s][n];
    A[n] = t;
  }

  const float4* sp = (const float4*)(seg   + (size_t)bf * NB * HW);
  const float4* mp = (const float4*)(masks + (size_t)bf * NS * HW);
  const float4* vp = (const float4*)(vis   + (size_t)bf * NS * HW);
  const float4* rp = (const float4*)(recon + (size_t)bf * NB * C * HW);
  const float4* tp = (const float4*)(rtgt  + (size_t)bf * C * HW);

  const int q = chunk * TPB + threadIdx.x;  // float4 index: 4 contiguous pixels

  constexpr float INV_HW = 1.0f / (float)HW;
  constexpr float COEF = 0.1f / (float)C;

  // wt[n] = sum_s a[s][n]*t_s ; wv[n] = sum_s a[s][n]*vis_s  (per component)
  float4 wt[NB], wv[NB];
  #pragma unroll
  for (int n = 0; n < NB; ++n) {
    wt[n] = make_float4(0.f, 0.f, 0.f, 0.f);
    wv[n] = make_float4(0.f, 0.f, 0.f, 0.f);
  }
  #pragma unroll
  for (int s = 0; s < NS; ++s) {
    const float4 t4 = step05(mp[s * HW4 + q]);
    const float4 v4 = step05(vp[s * HW4 + q]);
    #pragma unroll
    for (int n = 0; n < NB; ++n) {
      fma4(wt[n], a[s][n], t4);
      fma4(wv[n], a[s][n], v4);
    }
  }

  float4 tg[C];
  #pragma unroll
  for (int c = 0; c < C; ++c) tg[c] = tp[c * HW4 + q];

  float4 acc4 = make_float4(0.f, 0.f, 0.f, 0.f);
  #pragma unroll
  for (int n = 0; n < NB; ++n) {
    float4 p = sp[n * HW4 + q];
    p.x = fminf(fmaxf(p.x, EPS), 1.0f - EPS);
    p.y = fminf(fmaxf(p.y, EPS), 1.0f - EPS);
    p.z = fminf(fmaxf(p.z, EPS), 1.0f - EPS);
    p.w = fminf(fmaxf(p.w, EPS), 1.0f - EPS);
    const float4 lp = make_float4(logf(p.x), logf(p.y), logf(p.z), logf(p.w));
    const float4 l1 = make_float4(log1pf(-p.x), log1pf(-p.y),
                                  log1pf(-p.z), log1pf(-p.w));
    float4 d2 = make_float4(0.f, 0.f, 0.f, 0.f);
    #pragma unroll
    for (int c = 0; c < C; ++c) {
      const float4 r = rp[(n * C + c) * HW4 + q];
      const float dx = r.x - tg[c].x, dy = r.y - tg[c].y;
      const float dz = r.z - tg[c].z, dw = r.w - tg[c].w;
      d2.x = fmaf(dx, dx, d2.x); d2.y = fmaf(dy, dy, d2.y);
      d2.z = fmaf(dz, dz, d2.z); d2.w = fmaf(dw, dw, d2.w);
    }
    // acc += -((lp-l1)*wt + l1*A)/HW + (0.1/C)*d2*wv   (per component)
    acc4.x += -((lp.x - l1.x) * wt[n].x + l1.x * A[n]) * INV_HW + COEF * d2.x * wv[n].x;
    acc4.y += -((lp.y - l1.y) * wt[n].y + l1.y * A[n]) * INV_HW + COEF * d2.y * wv[n].y;
    acc4.z += -((lp.z - l1.z) * wt[n].z + l1.z * A[n]) * INV_HW + COEF * d2.z * wv[n].z;
    acc4.w += -((lp.w - l1.w) * wt[n].w + l1.w * A[n]) * INV_HW + COEF * d2.w * wv[n].w;
  }

  float acc = (acc4.x + acc4.y) + (acc4.z + acc4.w);

  // wave(64) shuffle reduce -> LDS across 4 waves -> one atomic per block
  #pragma unroll
  for (int off = 32; off > 0; off >>= 1)
    acc += __shfl_down(acc, off, 64);

  __shared__ float wsum[TPB / 64];
  const int lane = threadIdx.x & 63;
  const int wid = threadIdx.x >> 6;
  if (lane == 0) wsum[wid] = acc;
  __syncthreads();
  if (threadIdx.x == 0) {
    float s = 0.f;
    #pragma unroll
    for (int i = 0; i < TPB / 64; ++i) s += wsum[i];
    constexpr float SCALE = 20.0f / (float)(B * FM1 * NB * NS);
    atomicAdd(out, s * SCALE);
  }
}

extern "C" void kernel_launch(void* const* d_in, const int* in_sizes, int n_in,
                              void* d_out, int out_size, void* d_ws, size_t ws_size,
                              hipStream_t stream) {
  const float* seg   = (const float*)d_in[0];
  const float* masks = (const float*)d_in[1];
  const float* recon = (const float*)d_in[2];
  const float* rtgt  = (const float*)d_in[3];
  const float* vis   = (const float*)d_in[4];
  const float* attn  = (const float*)d_in[5];

  float* out = (float*)d_out;
  hipMemsetAsync(out, 0, sizeof(float), stream);

  const int grid = PAIRS * BLOCKS_PER_PAIR;  // 1440 blocks
  em_rec_loss_kernel<<<grid, TPB, 0, stream>>>(seg, masks, recon, rtgt, vis, attn, out);
}

// Round 3
// 257.436 us; speedup vs baseline: 1.1739x; 1.0246x over previous
//
#include <hip/hip_runtime.h>

#define TPB 256

namespace {
constexpr int B = 8, F = 6, NB = 5, NS = 7, H = 192, W = 192, C = 3;
constexpr int FM1 = F - 1;                 // frames 1..5
constexpr int HW = H * W;                  // 36864
constexpr int HW4 = HW / 4;                // 9216 float4 per plane
constexpr int PAIRS = B * FM1;             // 40
constexpr int BLOCKS_PER_PAIR = HW4 / TPB; // 36
constexpr float EPS = 1e-7f;
constexpr float LN2 = 0.69314718055994530942f;
constexpr float K_BCE = LN2 / (float)HW;   // folds ln2 and 1/HW
constexpr float COEF = 0.1f / (float)C;    // mse coefficient
}

__device__ __forceinline__ float4 step05(float4 v) {
  return make_float4(v.x > 0.5f ? 1.f : 0.f, v.y > 0.5f ? 1.f : 0.f,
                     v.z > 0.5f ? 1.f : 0.f, v.w > 0.5f ? 1.f : 0.f);
}
__device__ __forceinline__ void fma4(float4& acc, float s, const float4& v) {
  acc.x = fmaf(s, v.x, acc.x); acc.y = fmaf(s, v.y, acc.y);
  acc.z = fmaf(s, v.z, acc.z); acc.w = fmaf(s, v.w, acc.w);
}
__device__ __forceinline__ float clampp(float p) {
  return __builtin_amdgcn_fmed3f(p, EPS, 1.0f - EPS);  // v_med3_f32, 1 inst
}

__global__ __launch_bounds__(TPB) void em_rec_loss_kernel(
    const float* __restrict__ seg,    // [B,F,NB,H,W]
    const float* __restrict__ masks,  // [B,F,NS,H,W]
    const float* __restrict__ recon,  // [B,F,NB,C,H,W]
    const float* __restrict__ rtgt,   // [B,F,C,H,W]
    const float* __restrict__ vis,    // [B,F,NS,H,W]
    const float* __restrict__ attn,   // [B,F,NS,NB]
    float* __restrict__ out)
{
  const int blk = blockIdx.x;
  const int pair = blk / BLOCKS_PER_PAIR;
  const int chunk = blk - pair * BLOCKS_PER_PAIR;
  const int b = pair / FM1;
  const int f = pair - b * FM1 + 1;
  const int bf = b * F + f;

  // Block-uniform attn weights, pre-scaled so the per-pixel math needs no
  // extra multiplies:  aw = a*(ln2/HW) for the BCE path, av = a*(0.1/C)
  // for the MSE path. AK[n] = (sum_s a)*ln2/HW weights the log(1-p) base.
  float aw[NS][NB], av[NS][NB];
  const float* at = attn + (size_t)bf * NS * NB;
  #pragma unroll
  for (int s = 0; s < NS; ++s)
    #pragma unroll
    for (int n = 0; n < NB; ++n) {
      const float a = at[s * NB + n];
      aw[s][n] = a * K_BCE;
      av[s][n] = a * COEF;
    }
  float AK[NB];
  #pragma unroll
  for (int n = 0; n < NB; ++n) {
    float t = 0.f;
    #pragma unroll
    for (int s = 0; s < NS; ++s) t += aw[s][n];
    AK[n] = t;
  }

  const float4* sp = (const float4*)(seg   + (size_t)bf * NB * HW);
  const float4* mp = (const float4*)(masks + (size_t)bf * NS * HW);
  const float4* vp = (const float4*)(vis   + (size_t)bf * NS * HW);
  const float4* rp = (const float4*)(recon + (size_t)bf * NB * C * HW);
  const float4* tp = (const float4*)(rtgt  + (size_t)bf * C * HW);

  const int q = chunk * TPB + threadIdx.x;  // float4 index (4 contiguous px)

  // ---- issue the cheap-to-consume loads first (independent, 18 dwordx4) ----
  float4 m4[NS], v4[NS];
  #pragma unroll
  for (int s = 0; s < NS; ++s) m4[s] = mp[s * HW4 + q];
  #pragma unroll
  for (int s = 0; s < NS; ++s) v4[s] = vp[s * HW4 + q];
  float4 tg[C];
  #pragma unroll
  for (int c = 0; c < C; ++c) tg[c] = tp[c * HW4 + q];
  float4 p4[NB];
  #pragma unroll
  for (int n = 0; n < NB; ++n) p4[n] = sp[n * HW4 + q];

  // wt[n] = sum_s aw[s][n]*t_s ; wv[n] = sum_s av[s][n]*vis_s  (per comp)
  float4 wt[NB], wv[NB];
  #pragma unroll
  for (int n = 0; n < NB; ++n) {
    wt[n] = make_float4(0.f, 0.f, 0.f, 0.f);
    wv[n] = make_float4(0.f, 0.f, 0.f, 0.f);
  }
  #pragma unroll
  for (int s = 0; s < NS; ++s) {
    const float4 t4 = step05(m4[s]);
    const float4 vv = step05(v4[s]);
    #pragma unroll
    for (int n = 0; n < NB; ++n) {
      fma4(wt[n], aw[s][n], t4);
      fma4(wv[n], av[s][n], vv);
    }
  }

  float4 acc4 = make_float4(0.f, 0.f, 0.f, 0.f);
  #pragma unroll
  for (int n = 0; n < NB; ++n) {
    // seg BCE:  contrib = g * (-wt) + g1 * (wt - AK),  g = log2(p) etc.
    float4 p = p4[n];
    p.x = clampp(p.x); p.y = clampp(p.y); p.z = clampp(p.z); p.w = clampp(p.w);
    const float4 g  = make_float4(__log2f(p.x), __log2f(p.y),
                                  __log2f(p.z), __log2f(p.w));
    const float4 g1 = make_float4(__log2f(1.0f - p.x), __log2f(1.0f - p.y),
                                  __log2f(1.0f - p.z), __log2f(1.0f - p.w));
    float4 d2 = make_float4(0.f, 0.f, 0.f, 0.f);
    #pragma unroll
    for (int c = 0; c < C; ++c) {
      const float4 r = rp[(n * C + c) * HW4 + q];
      const float dx = r.x - tg[c].x, dy = r.y - tg[c].y;
      const float dz = r.z - tg[c].z, dw = r.w - tg[c].w;
      d2.x = fmaf(dx, dx, d2.x); d2.y = fmaf(dy, dy, d2.y);
      d2.z = fmaf(dz, dz, d2.z); d2.w = fmaf(dw, dw, d2.w);
    }
    acc4.x = fmaf(g.x, -wt[n].x, fmaf(g1.x, wt[n].x - AK[n], fmaf(d2.x, wv[n].x, acc4.x)));
    acc4.y = fmaf(g.y, -wt[n].y, fmaf(g1.y, wt[n].y - AK[n], fmaf(d2.y, wv[n].y, acc4.y)));
    acc4.z = fmaf(g.z, -wt[n].z, fmaf(g1.z, wt[n].z - AK[n], fmaf(d2.z, wv[n].z, acc4.z)));
    acc4.w = fmaf(g.w, -wt[n].w, fmaf(g1.w, wt[n].w - AK[n], fmaf(d2.w, wv[n].w, acc4.w)));
  }

  float acc = (acc4.x + acc4.y) + (acc4.z + acc4.w);

  // wave(64) shuffle reduce -> LDS across 4 waves -> one atomic per block
  #pragma unroll
  for (int off = 32; off > 0; off >>= 1)
    acc += __shfl_down(acc, off, 64);

  __shared__ float wsum[TPB / 64];
  const int lane = threadIdx.x & 63;
  const int wid = threadIdx.x >> 6;
  if (lane == 0) wsum[wid] = acc;
  __syncthreads();
  if (threadIdx.x == 0) {
    float s = 0.f;
    #pragma unroll
    for (int i = 0; i < TPB / 64; ++i) s += wsum[i];
    constexpr float SCALE = 20.0f / (float)(B * FM1 * NB * NS);
    atomicAdd(out, s * SCALE);
  }
}

extern "C" void kernel_launch(void* const* d_in, const int* in_sizes, int n_in,
                              void* d_out, int out_size, void* d_ws, size_t ws_size,
                              hipStream_t stream) {
  const float* seg   = (const float*)d_in[0];
  const float* masks = (const float*)d_in[1];
  const float* recon = (const float*)d_in[2];
  const float* rtgt  = (const float*)d_in[3];
  const float* vis   = (const float*)d_in[4];
  const float* attn  = (const float*)d_in[5];

  float* out = (float*)d_out;
  hipMemsetAsync(out, 0, sizeof(float), stream);

  const int grid = PAIRS * BLOCKS_PER_PAIR;  // 1440 blocks
  em_rec_loss_kernel<<<grid, TPB, 0, stream>>>(seg, masks, recon, rtgt, vis, attn, out);
}